// Round 2
// baseline (854.609 us; speedup 1.0000x reference)
//
#include <hip/hip_runtime.h>

#define NB   256
#define NT   512
#define DHX  100   // DX
#define DHZ  100   // DZ
#define DOUT 500
#define RING 16    // h1 ring depth (2 windows)

__device__ __forceinline__ float sgm(float v) { return 1.f / (1.f + __expf(-v)); }
__device__ __forceinline__ float tnh(float v) {
    v = fminf(fmaxf(v, -15.f), 15.f);
    float e = __expf(2.f * v);
    return (e - 1.f) / (e + 1.f);
}
__device__ __forceinline__ float sftp(float v) {
    return fmaxf(v, 0.f) + __logf(1.f + __expf(-fabsf(v)));
}
__device__ __forceinline__ float rdlane(float v, int k) {
    return __uint_as_float(__builtin_amdgcn_readlane(__float_as_uint(v), (unsigned)k));
}

// One block (128 threads = 2 waves) per batch element.
// wave0: h1 recurrence (dz MLP -> z reparam -> GRU1) + z outputs.
// wave1: h2 recurrence (GRU2 over x) + dx MLP + x outputs, one 8-step window
//        behind wave0 (reads h1 from a 16-deep LDS ring).
// Head/MLP weights live in LDS in [read-idx][lane] float4 layout (conflict-free,
// static addresses -> reads issue at step top, latency hidden). Only the
// GRU input matrices (wA/wB, on the z/x matvec critical path) + W_hh stay in
// registers, so per-wave VGPR demand fits without AGPR/scratch shuffling.
// All global pointers march (SGPR base += stride) -> no per-step 64-bit mults.
__global__ __launch_bounds__(128, 1) void arfssm(
    const float* __restrict__ x, const float* __restrict__ eps,
    const float* __restrict__ W_ih1, const float* __restrict__ W_hh1,
    const float* __restrict__ b_ih1, const float* __restrict__ b_hh1,
    const float* __restrict__ W_ih2, const float* __restrict__ W_hh2,
    const float* __restrict__ b_ih2, const float* __restrict__ b_hh2,
    const float* __restrict__ dz_W1, const float* __restrict__ dz_b1,
    const float* __restrict__ dz_Wloc, const float* __restrict__ dz_bloc,
    const float* __restrict__ dz_Wscale, const float* __restrict__ dz_bscale,
    const float* __restrict__ dx_W1, const float* __restrict__ dx_b1,
    const float* __restrict__ dx_Wloc, const float* __restrict__ dx_bloc,
    const float* __restrict__ dx_Wscale, const float* __restrict__ dx_bscale,
    const float* __restrict__ h1_0, const float* __restrict__ h2_0,
    float* __restrict__ out)
{
    __shared__ __align__(16) float h1d[RING][12];  // h1 ring
    __shared__ __align__(16) float xbuf[2][104];   // wave1 x row double buffer
    __shared__ __align__(16) float zbuf[104];      // wave0 z_t
    __shared__ float4 WZ0[20 * 64];  // wave0 head weights: r<5 loc[l], 5..9 scale[l], 10..14 loc[l+64], 15..19 scale[l+64]
    __shared__ float4 DZ1[3 * 64];   // wave0 dz_W1 row l (10 floats, padded to 12)
    __shared__ float4 WX1[20 * 64];  // wave1 head weights (dx_Wloc/dx_Wscale), same layout
    __shared__ float4 DX1[5 * 64];   // wave1 dx_W1 row l (20 floats)

    const int tid = threadIdx.x;
    const int b   = blockIdx.x;

    if (tid < 64) {
        // ============================ WAVE 0 ============================
        const int l = tid;

        // ---- LDS weight staging (one-time; same-wave in-order ds ops) ----
        #pragma unroll
        for (int r = 0; r < 5; ++r) {
            const float* p = dz_Wloc + l * 20 + r * 4;
            WZ0[r * 64 + l] = make_float4(p[0], p[1], p[2], p[3]);
            const float* q = dz_Wscale + l * 20 + r * 4;
            WZ0[(r + 5) * 64 + l] = make_float4(q[0], q[1], q[2], q[3]);
            float4 v2 = make_float4(0.f, 0.f, 0.f, 0.f);
            float4 s2 = make_float4(0.f, 0.f, 0.f, 0.f);
            if (l < 36) {
                const float* p2 = dz_Wloc + (l + 64) * 20 + r * 4;
                v2 = make_float4(p2[0], p2[1], p2[2], p2[3]);
                const float* q2 = dz_Wscale + (l + 64) * 20 + r * 4;
                s2 = make_float4(q2[0], q2[1], q2[2], q2[3]);
            }
            WZ0[(r + 10) * 64 + l] = v2;
            WZ0[(r + 15) * 64 + l] = s2;
        }
        #pragma unroll
        for (int r = 0; r < 3; ++r) {
            float4 v = make_float4(0.f, 0.f, 0.f, 0.f);
            if (l < 20) {
                const int i0 = r * 4;
                v.x = dz_W1[l * 10 + i0];
                if (i0 + 1 < 10) v.y = dz_W1[l * 10 + i0 + 1];
                if (i0 + 2 < 10) v.z = dz_W1[l * 10 + i0 + 2];
                if (i0 + 3 < 10) v.w = dz_W1[l * 10 + i0 + 3];
            }
            DZ1[r * 64 + l] = v;
        }

        // ---- register weights: GRU1 input matrix (split-K pairs) + W_hh1 ----
        const float bdz1 = (l < 20) ? dz_b1[l] : 0.f;
        const float bzl1 = dz_bloc[l], bzs1 = dz_bscale[l];
        const float bzl2 = (l < 36) ? dz_bloc[l + 64] : 0.f;
        const float bzs2 = (l < 36) ? dz_bscale[l + 64] : 0.f;
        const int gi_i = l >> 1, gi_h = l & 1;
        float wA[52]; float bih_p = 0.f, bhh_p = 0.f; float whh_p[10];
        #pragma unroll
        for (int k = 0; k < 52; ++k) wA[k] = 0.f;
        #pragma unroll
        for (int k = 0; k < 10; ++k) whh_p[k] = 0.f;
        if (l < 60) {
            const int k0 = gi_h ? 52 : 0;
            const int kn = gi_h ? 48 : 52;
            #pragma unroll
            for (int k = 0; k < 52; ++k) if (k < kn) wA[k] = W_ih1[gi_i * 100 + k0 + k];
            bih_p = b_ih1[gi_i];
            bhh_p = b_hh1[gi_i];
            #pragma unroll
            for (int k = 0; k < 10; ++k) whh_p[k] = W_hh1[gi_i * 10 + k];
        }

        // ---- state: h1 wave-uniform + per-lane copy in lanes 0..9 ----
        float hs[10];
        #pragma unroll
        for (int k = 0; k < 10; ++k) hs[k] = h1_0[k];
        float h1own = (l < 10) ? h1_0[l] : 0.f;
        if (l < 10) h1d[0][l] = h1_0[l];
        if (l < 4)  zbuf[100 + l] = 0.f;

        // ---- marched pointers ----
        const float* eprow = eps + (size_t)b * NT * DHZ;      // row 0
        float e1c = eprow[l];
        float e2c = (l < 36) ? eprow[64 + l] : 0.f;
        eprow += DHZ;                                          // prefetch row = 1
        float* op0 = out + (size_t)b * NT * DOUT;

        for (int w = 0; w < 64; ++w) {
            #pragma unroll 1
            for (int i = 0; i < 8; ++i) {
                const int t   = 8 * w + i;
                const int wsl = (t + 1) & (RING - 1);

                // gh1 (depends only on hs) -- fills latency window
                float gh = bhh_p;
                #pragma unroll
                for (int k = 0; k < 10; ++k) gh = fmaf(whh_p[k], hs[k], gh);

                // dz hidden from LDS weights
                float4 d0 = DZ1[l], d1 = DZ1[64 + l], d2 = DZ1[128 + l];
                float hv = bdz1;
                hv = fmaf(d0.x, hs[0], hv); hv = fmaf(d0.y, hs[1], hv);
                hv = fmaf(d0.z, hs[2], hv); hv = fmaf(d0.w, hs[3], hv);
                hv = fmaf(d1.x, hs[4], hv); hv = fmaf(d1.y, hs[5], hv);
                hv = fmaf(d1.z, hs[6], hv); hv = fmaf(d1.w, hs[7], hv);
                hv = fmaf(d2.x, hs[8], hv); hv = fmaf(d2.y, hs[9], hv);
                hv = fmaxf(hv, 0.f);
                float hd[20];
                #pragma unroll
                for (int k = 0; k < 20; ++k) hd[k] = rdlane(hv, k);

                // eps prefetch (marched pointer)
                float e1n = eprow[l];
                float e2n = (l < 36) ? eprow[64 + l] : 0.f;

                // z heads from LDS weights (accumulation order preserved)
                float vl1 = bzl1, vs1 = bzs1;
                #pragma unroll
                for (int q = 0; q < 5; ++q) {
                    float4 a = WZ0[q * 64 + l];
                    float4 s = WZ0[(q + 5) * 64 + l];
                    vl1 = fmaf(a.x, hd[4*q+0], vl1); vl1 = fmaf(a.y, hd[4*q+1], vl1);
                    vl1 = fmaf(a.z, hd[4*q+2], vl1); vl1 = fmaf(a.w, hd[4*q+3], vl1);
                    vs1 = fmaf(s.x, hd[4*q+0], vs1); vs1 = fmaf(s.y, hd[4*q+1], vs1);
                    vs1 = fmaf(s.z, hd[4*q+2], vs1); vs1 = fmaf(s.w, hd[4*q+3], vs1);
                }
                float vl2 = bzl2, vs2 = bzs2;
                #pragma unroll
                for (int q = 0; q < 5; ++q) {
                    float4 a = WZ0[(q + 10) * 64 + l];
                    float4 s = WZ0[(q + 15) * 64 + l];
                    vl2 = fmaf(a.x, hd[4*q+0], vl2); vl2 = fmaf(a.y, hd[4*q+1], vl2);
                    vl2 = fmaf(a.z, hd[4*q+2], vl2); vl2 = fmaf(a.w, hd[4*q+3], vl2);
                    vs2 = fmaf(s.x, hd[4*q+0], vs2); vs2 = fmaf(s.y, hd[4*q+1], vs2);
                    vs2 = fmaf(s.z, hd[4*q+2], vs2); vs2 = fmaf(s.w, hd[4*q+3], vs2);
                }
                float sp1 = sftp(vs1), sp2 = sftp(vs2);
                float zt1 = fmaf(sp1, e1c, vl1);
                float zt2 = fmaf(sp2, e2c, vl2);
                zbuf[l] = zt1;
                if (l < 36) zbuf[64 + l] = zt2;
                __builtin_amdgcn_wave_barrier();

                // z outputs (marched base -> imm-offset stores)
                op0[200 + l] = vl1; op0[300 + l] = sp1; op0[400 + l] = zt1;
                if (l < 36) { op0[264 + l] = vl2; op0[364 + l] = sp2; op0[464 + l] = zt2; }
                e1c = e1n; e2c = e2n;

                // gi1 = W_ih1 @ z_t (split-K lane pairs, wA in registers)
                const float4* z4 = (const float4*)zbuf;
                const int b4 = gi_h ? 13 : 0;
                float a0 = 0.f, a1 = 0.f, a2 = 0.f, a3 = 0.f;
                #pragma unroll
                for (int q = 0; q < 13; ++q) {
                    float4 zz = z4[b4 + q];
                    a0 = fmaf(wA[4*q+0], zz.x, a0);
                    a1 = fmaf(wA[4*q+1], zz.y, a1);
                    a2 = fmaf(wA[4*q+2], zz.z, a2);
                    a3 = fmaf(wA[4*q+3], zz.w, a3);
                }
                float acc = (a0 + a1) + (a2 + a3);
                acc += __shfl_xor(acc, 1, 64);
                float gih  = acc + bih_p;
                float gsum = gih + gh;

                // gate gathers
                float s_r  = __shfl(gsum, 2 * l,      64);
                float s_u  = __shfl(gsum, 2 * l + 20, 64);
                float g_in = __shfl(gih,  2 * l + 40, 64);
                float g_hn = __shfl(gh,   2 * l + 40, 64);
                float r = sgm(s_r), u = sgm(s_u);
                float n = tnh(fmaf(r, g_hn, g_in));
                float h1n_v = (1.f - u) * n + u * h1own;  // lanes 0..9

                if (l < 10) h1d[wsl][l] = h1n_v;
                #pragma unroll
                for (int k = 0; k < 10; ++k) hs[k] = rdlane(h1n_v, k);
                h1own = h1n_v;

                op0 += DOUT;
                if (t + 2 < NT) eprow += DHZ;
            }
            __syncthreads();   // end of window w
        }
        __syncthreads();       // window 64 (wave1 epilogue window)
    } else {
        // ============================ WAVE 1 ============================
        const int l = tid - 64;

        // ---- LDS weight staging ----
        #pragma unroll
        for (int r = 0; r < 5; ++r) {
            const float* p = dx_Wloc + l * 20 + r * 4;
            WX1[r * 64 + l] = make_float4(p[0], p[1], p[2], p[3]);
            const float* q = dx_Wscale + l * 20 + r * 4;
            WX1[(r + 5) * 64 + l] = make_float4(q[0], q[1], q[2], q[3]);
            float4 v2 = make_float4(0.f, 0.f, 0.f, 0.f);
            float4 s2 = make_float4(0.f, 0.f, 0.f, 0.f);
            if (l < 36) {
                const float* p2 = dx_Wloc + (l + 64) * 20 + r * 4;
                v2 = make_float4(p2[0], p2[1], p2[2], p2[3]);
                const float* q2 = dx_Wscale + (l + 64) * 20 + r * 4;
                s2 = make_float4(q2[0], q2[1], q2[2], q2[3]);
            }
            WX1[(r + 10) * 64 + l] = v2;
            WX1[(r + 15) * 64 + l] = s2;
        }
        #pragma unroll
        for (int r = 0; r < 5; ++r) {
            float4 v = make_float4(0.f, 0.f, 0.f, 0.f);
            if (l < 20) {
                const float* p = dx_W1 + l * 20 + r * 4;
                v = make_float4(p[0], p[1], p[2], p[3]);
            }
            DX1[r * 64 + l] = v;
        }

        const float bdx1 = (l < 20) ? dx_b1[l] : 0.f;
        const float bxl1 = dx_bloc[l], bxs1 = dx_bscale[l];
        const float bxl2 = (l < 36) ? dx_bloc[l + 64] : 0.f;
        const float bxs2 = (l < 36) ? dx_bscale[l + 64] : 0.f;
        const int gi_i = l >> 1, gi_h = l & 1;
        float wB[52]; float bih_p = 0.f, bhh_p = 0.f; float whh_p[10];
        #pragma unroll
        for (int k = 0; k < 52; ++k) wB[k] = 0.f;
        #pragma unroll
        for (int k = 0; k < 10; ++k) whh_p[k] = 0.f;
        if (l < 60) {
            const int k0 = gi_h ? 52 : 0;
            const int kn = gi_h ? 48 : 52;
            #pragma unroll
            for (int k = 0; k < 52; ++k) if (k < kn) wB[k] = W_ih2[gi_i * 100 + k0 + k];
            bih_p = b_ih2[gi_i];
            bhh_p = b_hh2[gi_i];
            #pragma unroll
            for (int k = 0; k < 10; ++k) whh_p[k] = W_hh2[gi_i * 10 + k];
        }

        // ---- state: h2 wave-uniform + per-lane copy ----
        float hs2[10];
        #pragma unroll
        for (int k = 0; k < 10; ++k) hs2[k] = h2_0[k];
        float h2own = (l < 10) ? h2_0[l] : 0.f;

        // ---- prologue: x row 0 -> xbuf[0], row 1 -> vh; marched pointers ----
        if (l < 4) { xbuf[0][100 + l] = 0.f; xbuf[1][100 + l] = 0.f; }
        float4 vh = make_float4(0.f, 0.f, 0.f, 0.f);
        if (l < 25) {
            const float4* xr0 = (const float4*)(x + (size_t)b * NT * DHX);
            const float4* xr1 = (const float4*)(x + ((size_t)b * NT + 1) * DHX);
            float4 v0 = xr0[l];
            vh = xr1[l];
            *((float4*)&xbuf[0][0] + l) = v0;
        }
        const float* xrow = x + (size_t)b * NT * DHX + 2 * DHX;  // prefetch row = 2
        float* op1 = out + (size_t)b * NT * DOUT;

        __syncthreads();       // window 0 (wave0 fills h1 slots 1..8)
        for (int w = 1; w < 65; ++w) {
            #pragma unroll 1
            for (int i = 0; i < 8; ++i) {
                const int t = 8 * (w - 1) + i;

                // publish x(t+1); prefetch x(t+2) (marched)
                if (l < 25) *((float4*)&xbuf[(t + 1) & 1][0] + l) = vh;
                if (l < 25) vh = ((const float4*)xrow)[l];

                // h1n(t) ring read, issued early
                const int hsl = (t + 1) & (RING - 1);
                float4 ha = *(const float4*)&h1d[hsl][0];
                float4 hb = *(const float4*)&h1d[hsl][4];
                float h8 = h1d[hsl][8], h9 = h1d[hsl][9];

                // GRU2 gi2 from xbuf[t&1] (wB in registers)
                const float4* x4 = (const float4*)&xbuf[t & 1][0];
                const int b4 = gi_h ? 13 : 0;
                float a0 = 0.f, a1 = 0.f, a2 = 0.f, a3 = 0.f;
                #pragma unroll
                for (int q = 0; q < 13; ++q) {
                    float4 xx = x4[b4 + q];
                    a0 = fmaf(wB[4*q+0], xx.x, a0);
                    a1 = fmaf(wB[4*q+1], xx.y, a1);
                    a2 = fmaf(wB[4*q+2], xx.z, a2);
                    a3 = fmaf(wB[4*q+3], xx.w, a3);
                }
                float acc = (a0 + a1) + (a2 + a3);
                acc += __shfl_xor(acc, 1, 64);
                float gh = bhh_p;
                #pragma unroll
                for (int k = 0; k < 10; ++k) gh = fmaf(whh_p[k], hs2[k], gh);
                float gih  = acc + bih_p;
                float gsum = gih + gh;
                // gate gathers issued now; latency hides under dx MLP
                float s_r  = __shfl(gsum, 2 * l,      64);
                float s_u  = __shfl(gsum, 2 * l + 20, 64);
                float g_in = __shfl(gih,  2 * l + 40, 64);
                float g_hn = __shfl(gh,   2 * l + 40, 64);

                // dx hidden from LDS weights: [h1n(t), h2_shift(t)]
                float4 d0 = DX1[l], d1 = DX1[64 + l], d2 = DX1[128 + l],
                       d3 = DX1[192 + l], d4 = DX1[256 + l];
                float hv = bdx1;
                hv = fmaf(d0.x, ha.x, hv); hv = fmaf(d0.y, ha.y, hv);
                hv = fmaf(d0.z, ha.z, hv); hv = fmaf(d0.w, ha.w, hv);
                hv = fmaf(d1.x, hb.x, hv); hv = fmaf(d1.y, hb.y, hv);
                hv = fmaf(d1.z, hb.z, hv); hv = fmaf(d1.w, hb.w, hv);
                hv = fmaf(d2.x, h8, hv);   hv = fmaf(d2.y, h9, hv);
                hv = fmaf(d2.z, hs2[0], hv); hv = fmaf(d2.w, hs2[1], hv);
                hv = fmaf(d3.x, hs2[2], hv); hv = fmaf(d3.y, hs2[3], hv);
                hv = fmaf(d3.z, hs2[4], hv); hv = fmaf(d3.w, hs2[5], hv);
                hv = fmaf(d4.x, hs2[6], hv); hv = fmaf(d4.y, hs2[7], hv);
                hv = fmaf(d4.z, hs2[8], hv); hv = fmaf(d4.w, hs2[9], hv);
                hv = fmaxf(hv, 0.f);
                float hx[20];
                #pragma unroll
                for (int k = 0; k < 20; ++k) hx[k] = rdlane(hv, k);

                // x heads from LDS weights
                float vl1 = bxl1, vs1 = bxs1;
                #pragma unroll
                for (int q = 0; q < 5; ++q) {
                    float4 a = WX1[q * 64 + l];
                    float4 s = WX1[(q + 5) * 64 + l];
                    vl1 = fmaf(a.x, hx[4*q+0], vl1); vl1 = fmaf(a.y, hx[4*q+1], vl1);
                    vl1 = fmaf(a.z, hx[4*q+2], vl1); vl1 = fmaf(a.w, hx[4*q+3], vl1);
                    vs1 = fmaf(s.x, hx[4*q+0], vs1); vs1 = fmaf(s.y, hx[4*q+1], vs1);
                    vs1 = fmaf(s.z, hx[4*q+2], vs1); vs1 = fmaf(s.w, hx[4*q+3], vs1);
                }
                float vl2 = bxl2, vs2 = bxs2;
                #pragma unroll
                for (int q = 0; q < 5; ++q) {
                    float4 a = WX1[(q + 10) * 64 + l];
                    float4 s = WX1[(q + 15) * 64 + l];
                    vl2 = fmaf(a.x, hx[4*q+0], vl2); vl2 = fmaf(a.y, hx[4*q+1], vl2);
                    vl2 = fmaf(a.z, hx[4*q+2], vl2); vl2 = fmaf(a.w, hx[4*q+3], vl2);
                    vs2 = fmaf(s.x, hx[4*q+0], vs2); vs2 = fmaf(s.y, hx[4*q+1], vs2);
                    vs2 = fmaf(s.z, hx[4*q+2], vs2); vs2 = fmaf(s.w, hx[4*q+3], vs2);
                }
                op1[l]       = vl1;
                op1[100 + l] = sftp(vs1);
                if (l < 36) { op1[64 + l] = vl2; op1[164 + l] = sftp(vs2); }

                // gates + h2 update
                float r = sgm(s_r), u = sgm(s_u);
                float n = tnh(fmaf(r, g_hn, g_in));
                float h2n_v = (1.f - u) * n + u * h2own;  // lanes 0..9
                #pragma unroll
                for (int k = 0; k < 10; ++k) hs2[k] = rdlane(h2n_v, k);
                h2own = h2n_v;

                op1 += DOUT;
                if (t + 3 < NT) xrow += DHX;
            }
            __syncthreads();   // end of window w
        }
    }
}

extern "C" void kernel_launch(void* const* d_in, const int* in_sizes, int n_in,
                              void* d_out, int out_size, void* d_ws, size_t ws_size,
                              hipStream_t stream) {
    (void)in_sizes; (void)n_in; (void)out_size; (void)d_ws; (void)ws_size;
    const float* x         = (const float*)d_in[0];
    const float* eps       = (const float*)d_in[1];
    const float* W_ih1     = (const float*)d_in[2];
    const float* W_hh1     = (const float*)d_in[3];
    const float* b_ih1     = (const float*)d_in[4];
    const float* b_hh1     = (const float*)d_in[5];
    const float* W_ih2     = (const float*)d_in[6];
    const float* W_hh2     = (const float*)d_in[7];
    const float* b_ih2     = (const float*)d_in[8];
    const float* b_hh2     = (const float*)d_in[9];
    const float* dz_W1     = (const float*)d_in[10];
    const float* dz_b1     = (const float*)d_in[11];
    const float* dz_Wloc   = (const float*)d_in[12];
    const float* dz_bloc   = (const float*)d_in[13];
    const float* dz_Wscale = (const float*)d_in[14];
    const float* dz_bscale = (const float*)d_in[15];
    const float* dx_W1     = (const float*)d_in[16];
    const float* dx_b1     = (const float*)d_in[17];
    const float* dx_Wloc   = (const float*)d_in[18];
    const float* dx_bloc   = (const float*)d_in[19];
    const float* dx_Wscale = (const float*)d_in[20];
    const float* dx_bscale = (const float*)d_in[21];
    const float* h1_0      = (const float*)d_in[22];
    const float* h2_0      = (const float*)d_in[23];

    arfssm<<<NB, 128, 0, stream>>>(x, eps, W_ih1, W_hh1, b_ih1, b_hh1,
                                   W_ih2, W_hh2, b_ih2, b_hh2,
                                   dz_W1, dz_b1, dz_Wloc, dz_bloc, dz_Wscale, dz_bscale,
                                   dx_W1, dx_b1, dx_Wloc, dx_bloc, dx_Wscale, dx_bscale,
                                   h1_0, h2_0, (float*)d_out);
}

// Round 3
// 822.077 us; speedup vs baseline: 1.0396x; 1.0396x over previous
//
#include <hip/hip_runtime.h>

#define NB   256
#define NT   512
#define DHX  100   // DX
#define DHZ  100   // DZ
#define DOUT 500
#define RING 16    // h1 ring depth (2 windows)
#define G2S  32    // gi2 row stride in workspace (30 used, padded)

__device__ __forceinline__ float sgm(float v) { return 1.f / (1.f + __expf(-v)); }
__device__ __forceinline__ float tnh(float v) {
    v = fminf(fmaxf(v, -15.f), 15.f);
    float e = __expf(2.f * v);
    return (e - 1.f) / (e + 1.f);
}
__device__ __forceinline__ float sftp(float v) {
    return fmaxf(v, 0.f) + __logf(1.f + __expf(-fabsf(v)));
}
__device__ __forceinline__ float rdlane(float v, int k) {
    return __uint_as_float(__builtin_amdgcn_readlane(__float_as_uint(v), (unsigned)k));
}
// pair-sum via DPP quad_perm [1,0,3,2]: returns v + v(lane^1). VALU-only,
// replaces ds_bpermute shfl_xor on the critical path.
__device__ __forceinline__ float dpp_xor1_add(float v) {
    int sw = __builtin_amdgcn_update_dpp(0, __float_as_int(v), 0xB1, 0xF, 0xF, true);
    return v + __int_as_float(sw);
}

// ============================================================================
// Phase A (fully parallel): gi2_all[b,t,i] = b_ih2[i] + sum_k W_ih2[i,k] x[b,t,k]
// for i = 0..29. One wave per row; lane pairs (i, i+32) split K 52/48,
// combine with shfl_xor(32). x-row reads are 2-address broadcast float4 loads.
// ============================================================================
__global__ __launch_bounds__(256, 1) void gi2_pre(
    const float* __restrict__ x, const float* __restrict__ W_ih2,
    const float* __restrict__ b_ih2, float* __restrict__ gi2)
{
    const int lane = threadIdx.x & 63;
    const int wid  = (blockIdx.x << 2) | (threadIdx.x >> 6);
    const int half = lane >> 5;          // 0: k=0..51, 1: k=52..99
    const int i    = lane & 31;          // output row (0..29 valid)

    float wk[52];
    #pragma unroll
    for (int k = 0; k < 52; ++k) wk[k] = 0.f;
    float bias = 0.f;
    if (i < 30) {
        const int k0 = half ? 52 : 0;
        const int kn = half ? 48 : 52;
        #pragma unroll
        for (int k = 0; k < 52; ++k) if (k < kn) wk[k] = W_ih2[i * 100 + k0 + k];
        bias = b_ih2[i];
    }

    const int NROW = NB * NT;
    for (int r = wid; r < NROW; r += 8192) {
        const float4* x4 = (const float4*)(x + (size_t)r * DHX);
        const int b4 = half ? 13 : 0;
        float a0 = 0.f, a1 = 0.f, a2 = 0.f, a3 = 0.f;
        #pragma unroll
        for (int q = 0; q < 12; ++q) {
            float4 v = x4[b4 + q];
            a0 = fmaf(wk[4*q+0], v.x, a0);
            a1 = fmaf(wk[4*q+1], v.y, a1);
            a2 = fmaf(wk[4*q+2], v.z, a2);
            a3 = fmaf(wk[4*q+3], v.w, a3);
        }
        if (!half) {   // extra quad for the 52-wide half
            float4 v = x4[12];
            a0 = fmaf(wk[48], v.x, a0);
            a1 = fmaf(wk[49], v.y, a1);
            a2 = fmaf(wk[50], v.z, a2);
            a3 = fmaf(wk[51], v.w, a3);
        }
        float acc = (a0 + a1) + (a2 + a3);
        acc += __shfl_xor(acc, 32, 64);
        if (half == 0 && i < 30) gi2[(size_t)r * G2S + i] = acc + bias;
    }
}

// ============================================================================
// Phase B: one block (128 threads = 2 waves) per batch element.
// wave0: h1 recurrence (dz MLP -> z reparam -> GRU1) + z outputs (round-1
//        register-weight structure + marched pointers + DPP pair-reduce).
// wave1: h2 recurrence using PRECOMPUTED gi2 (no x matvec, no xbuf!) + dx MLP
//        + x outputs, one 8-step window behind wave0 (LDS h1 ring).
// ============================================================================
__global__ __launch_bounds__(128, 1) void arfssm(
    const float* __restrict__ gi2, const float* __restrict__ eps,
    const float* __restrict__ W_ih1, const float* __restrict__ W_hh1,
    const float* __restrict__ b_ih1, const float* __restrict__ b_hh1,
    const float* __restrict__ W_hh2, const float* __restrict__ b_hh2,
    const float* __restrict__ dz_W1, const float* __restrict__ dz_b1,
    const float* __restrict__ dz_Wloc, const float* __restrict__ dz_bloc,
    const float* __restrict__ dz_Wscale, const float* __restrict__ dz_bscale,
    const float* __restrict__ dx_W1, const float* __restrict__ dx_b1,
    const float* __restrict__ dx_Wloc, const float* __restrict__ dx_bloc,
    const float* __restrict__ dx_Wscale, const float* __restrict__ dx_bscale,
    const float* __restrict__ h1_0, const float* __restrict__ h2_0,
    float* __restrict__ out)
{
    __shared__ __align__(16) float h1d[RING][12];  // h1 ring
    __shared__ __align__(16) float zbuf[104];      // wave0 z_t

    const int tid = threadIdx.x;
    const int b   = blockIdx.x;

    if (tid < 64) {
        // ============================ WAVE 0 ============================
        const int l = tid;

        // ---- per-lane weight preload (registers, round-1 layout) ----
        float wdz1[10]; float bdz1 = 0.f;
        #pragma unroll
        for (int k = 0; k < 10; ++k) wdz1[k] = 0.f;
        if (l < 20) {
            #pragma unroll
            for (int k = 0; k < 10; ++k) wdz1[k] = dz_W1[l * 10 + k];
            bdz1 = dz_b1[l];
        }
        float wzl1[20], wzs1[20];
        #pragma unroll
        for (int k = 0; k < 20; ++k) { wzl1[k] = dz_Wloc[l * 20 + k]; wzs1[k] = dz_Wscale[l * 20 + k]; }
        const float bzl1 = dz_bloc[l], bzs1 = dz_bscale[l];
        float wzl2[20], wzs2[20]; float bzl2 = 0.f, bzs2 = 0.f;
        #pragma unroll
        for (int k = 0; k < 20; ++k) { wzl2[k] = 0.f; wzs2[k] = 0.f; }
        if (l < 36) {
            const int j2 = l + 64;
            #pragma unroll
            for (int k = 0; k < 20; ++k) { wzl2[k] = dz_Wloc[j2 * 20 + k]; wzs2[k] = dz_Wscale[j2 * 20 + k]; }
            bzl2 = dz_bloc[j2]; bzs2 = dz_bscale[j2];
        }
        const int gi_i = l >> 1, gi_h = l & 1;
        float wA[52]; float bih_p = 0.f, bhh_p = 0.f; float whh_p[10];
        #pragma unroll
        for (int k = 0; k < 52; ++k) wA[k] = 0.f;
        #pragma unroll
        for (int k = 0; k < 10; ++k) whh_p[k] = 0.f;
        if (l < 60) {
            const int k0 = gi_h ? 52 : 0;
            const int kn = gi_h ? 48 : 52;
            #pragma unroll
            for (int k = 0; k < 52; ++k) if (k < kn) wA[k] = W_ih1[gi_i * 100 + k0 + k];
            bih_p = b_ih1[gi_i];
            bhh_p = b_hh1[gi_i];
            #pragma unroll
            for (int k = 0; k < 10; ++k) whh_p[k] = W_hh1[gi_i * 10 + k];
        }

        // ---- state: h1 wave-uniform + per-lane copy in lanes 0..9 ----
        float hs[10];
        #pragma unroll
        for (int k = 0; k < 10; ++k) hs[k] = h1_0[k];
        float h1own = (l < 10) ? h1_0[l] : 0.f;
        if (l < 4) zbuf[100 + l] = 0.f;

        // ---- marched pointers ----
        const float* eprow = eps + (size_t)b * NT * DHZ;
        float e1c = eprow[l];
        float e2c = (l < 36) ? eprow[64 + l] : 0.f;
        eprow += DHZ;
        float* op0 = out + (size_t)b * NT * DOUT;

        for (int w = 0; w < 64; ++w) {
            #pragma unroll 2
            for (int i = 0; i < 8; ++i) {
                const int t   = 8 * w + i;
                const int wsl = (t + 1) & (RING - 1);

                // gh1 (depends only on hs) -- fills latency window
                float gh = bhh_p;
                #pragma unroll
                for (int k = 0; k < 10; ++k) gh = fmaf(whh_p[k], hs[k], gh);

                // dz hidden
                float hv = bdz1;
                #pragma unroll
                for (int k = 0; k < 10; ++k) hv = fmaf(wdz1[k], hs[k], hv);
                hv = fmaxf(hv, 0.f);
                float hd[20];
                #pragma unroll
                for (int k = 0; k < 20; ++k) hd[k] = rdlane(hv, k);

                // eps prefetch (marched pointer)
                float e1n = eprow[l];
                float e2n = (l < 36) ? eprow[64 + l] : 0.f;

                // z heads
                float vl1 = bzl1, vs1 = bzs1, vl2 = bzl2, vs2 = bzs2;
                #pragma unroll
                for (int k = 0; k < 20; ++k) {
                    vl1 = fmaf(wzl1[k], hd[k], vl1); vs1 = fmaf(wzs1[k], hd[k], vs1);
                    vl2 = fmaf(wzl2[k], hd[k], vl2); vs2 = fmaf(wzs2[k], hd[k], vs2);
                }
                float sp1 = sftp(vs1), sp2 = sftp(vs2);
                float zt1 = fmaf(sp1, e1c, vl1);
                float zt2 = fmaf(sp2, e2c, vl2);
                zbuf[l] = zt1;
                if (l < 36) zbuf[64 + l] = zt2;
                __builtin_amdgcn_wave_barrier();

                // z outputs (marched base, imm-offset stores)
                op0[200 + l] = vl1; op0[300 + l] = sp1; op0[400 + l] = zt1;
                if (l < 36) { op0[264 + l] = vl2; op0[364 + l] = sp2; op0[464 + l] = zt2; }
                e1c = e1n; e2c = e2n;

                // gi1 = W_ih1 @ z_t (split-K lane pairs, wA in registers)
                const float4* z4 = (const float4*)zbuf;
                const int b4 = gi_h ? 13 : 0;
                float a0 = 0.f, a1 = 0.f, a2 = 0.f, a3 = 0.f;
                #pragma unroll
                for (int q = 0; q < 13; ++q) {
                    float4 zz = z4[b4 + q];
                    a0 = fmaf(wA[4*q+0], zz.x, a0);
                    a1 = fmaf(wA[4*q+1], zz.y, a1);
                    a2 = fmaf(wA[4*q+2], zz.z, a2);
                    a3 = fmaf(wA[4*q+3], zz.w, a3);
                }
                float acc = (a0 + a1) + (a2 + a3);
                acc = dpp_xor1_add(acc);               // pair sum, VALU-only
                float gih  = acc + bih_p;
                float gsum = gih + gh;

                // gate gathers
                float s_r  = __shfl(gsum, 2 * l,      64);
                float s_u  = __shfl(gsum, 2 * l + 20, 64);
                float g_in = __shfl(gih,  2 * l + 40, 64);
                float g_hn = __shfl(gh,   2 * l + 40, 64);
                float r = sgm(s_r), u = sgm(s_u);
                float n = tnh(fmaf(r, g_hn, g_in));
                float h1n_v = (1.f - u) * n + u * h1own;  // lanes 0..9

                if (l < 10) h1d[wsl][l] = h1n_v;
                #pragma unroll
                for (int k = 0; k < 10; ++k) hs[k] = rdlane(h1n_v, k);
                h1own = h1n_v;

                op0 += DOUT;
                if (t + 2 < NT) eprow += DHZ;
            }
            __syncthreads();   // end of window w
        }
        __syncthreads();       // window 64 (wave1 epilogue window)
    } else {
        // ============================ WAVE 1 ============================
        const int l = tid - 64;

        // ---- per-lane weight preload ----
        float wdx1[20]; float bdx1 = 0.f;
        #pragma unroll
        for (int k = 0; k < 20; ++k) wdx1[k] = 0.f;
        if (l < 20) {
            #pragma unroll
            for (int k = 0; k < 20; ++k) wdx1[k] = dx_W1[l * 20 + k];
            bdx1 = dx_b1[l];
        }
        float wxl1[20], wxs1[20];
        #pragma unroll
        for (int k = 0; k < 20; ++k) { wxl1[k] = dx_Wloc[l * 20 + k]; wxs1[k] = dx_Wscale[l * 20 + k]; }
        const float bxl1 = dx_bloc[l], bxs1 = dx_bscale[l];
        float wxl2[20], wxs2[20]; float bxl2 = 0.f, bxs2 = 0.f;
        #pragma unroll
        for (int k = 0; k < 20; ++k) { wxl2[k] = 0.f; wxs2[k] = 0.f; }
        if (l < 36) {
            const int j2 = l + 64;
            #pragma unroll
            for (int k = 0; k < 20; ++k) { wxl2[k] = dx_Wloc[j2 * 20 + k]; wxs2[k] = dx_Wscale[j2 * 20 + k]; }
            bxl2 = dx_bloc[j2]; bxs2 = dx_bscale[j2];
        }
        // GRU2 hidden weights: lane i<30 owns row i of W_hh2 (+ biases).
        float whh2r[10]; float bhh2 = 0.f;
        #pragma unroll
        for (int k = 0; k < 10; ++k) whh2r[k] = 0.f;
        if (l < 30) {
            #pragma unroll
            for (int k = 0; k < 10; ++k) whh2r[k] = W_hh2[l * 10 + k];
            bhh2 = b_hh2[l];
        }

        // ---- state: h2 wave-uniform + per-lane copy ----
        float hs2[10];
        #pragma unroll
        for (int k = 0; k < 10; ++k) hs2[k] = h2_0[k];
        float h2own = (l < 10) ? h2_0[l] : 0.f;

        // ---- gi2 stream (precomputed by phase A), marched pointer ----
        const float* g2p = gi2 + (size_t)b * NT * G2S;
        float gAc = (l < 30) ? g2p[l] : 0.f;   // row 0
        g2p += G2S;                             // prefetch row = 1
        float* op1 = out + (size_t)b * NT * DOUT;

        __syncthreads();       // window 0 (wave0 fills h1 slots 1..8)
        for (int w = 1; w < 65; ++w) {
            #pragma unroll 2
            for (int i = 0; i < 8; ++i) {
                const int t = 8 * (w - 1) + i;

                // prefetch gi2 row t+1
                float gAn = (l < 30) ? g2p[l] : 0.f;

                // h1n(t) ring read, issued early
                const int hsl = (t + 1) & (RING - 1);
                float4 ha = *(const float4*)&h1d[hsl][0];
                float4 hb = *(const float4*)&h1d[hsl][4];
                float h8 = h1d[hsl][8], h9 = h1d[hsl][9];

                // gh2 at lane i<30; gsum_i = gi2_i + gh_i (both with biases)
                float gh = bhh2;
                #pragma unroll
                for (int k = 0; k < 10; ++k) gh = fmaf(whh2r[k], hs2[k], gh);
                float gsum = gAc + gh;
                // gate gathers issued now; latency hides under dx MLP
                float s_u  = __shfl(gsum, l + 10, 64);
                float g_in = __shfl(gAc,  l + 20, 64);
                float g_hn = __shfl(gh,   l + 20, 64);

                // dx MLP for step t: [h1n(t) from ring, h2_shift(t) = hs2]
                float hv = bdx1;
                hv = fmaf(wdx1[0], ha.x, hv); hv = fmaf(wdx1[1], ha.y, hv);
                hv = fmaf(wdx1[2], ha.z, hv); hv = fmaf(wdx1[3], ha.w, hv);
                hv = fmaf(wdx1[4], hb.x, hv); hv = fmaf(wdx1[5], hb.y, hv);
                hv = fmaf(wdx1[6], hb.z, hv); hv = fmaf(wdx1[7], hb.w, hv);
                hv = fmaf(wdx1[8], h8, hv);   hv = fmaf(wdx1[9], h9, hv);
                #pragma unroll
                for (int k = 0; k < 10; ++k) hv = fmaf(wdx1[10 + k], hs2[k], hv);
                hv = fmaxf(hv, 0.f);
                float hx[20];
                #pragma unroll
                for (int k = 0; k < 20; ++k) hx[k] = rdlane(hv, k);

                // x heads
                float vl1 = bxl1, vs1 = bxs1, vl2 = bxl2, vs2 = bxs2;
                #pragma unroll
                for (int k = 0; k < 20; ++k) {
                    vl1 = fmaf(wxl1[k], hx[k], vl1); vs1 = fmaf(wxs1[k], hx[k], vs1);
                    vl2 = fmaf(wxl2[k], hx[k], vl2); vs2 = fmaf(wxs2[k], hx[k], vs2);
                }
                op1[l]       = vl1;
                op1[100 + l] = sftp(vs1);
                if (l < 36) { op1[64 + l] = vl2; op1[164 + l] = sftp(vs2); }

                // gates + h2 update (lane l<10: gsum_l is own value)
                float r = sgm(gsum);
                float u = sgm(s_u);
                float n = tnh(fmaf(r, g_hn, g_in));
                float h2n_v = (1.f - u) * n + u * h2own;  // lanes 0..9
                #pragma unroll
                for (int k = 0; k < 10; ++k) hs2[k] = rdlane(h2n_v, k);
                h2own = h2n_v;

                op1 += DOUT;
                gAc = gAn;
                if (t + 2 < NT) g2p += G2S;
            }
            __syncthreads();   // end of window w
        }
    }
}

extern "C" void kernel_launch(void* const* d_in, const int* in_sizes, int n_in,
                              void* d_out, int out_size, void* d_ws, size_t ws_size,
                              hipStream_t stream) {
    (void)in_sizes; (void)n_in; (void)out_size; (void)ws_size;
    const float* x         = (const float*)d_in[0];
    const float* eps       = (const float*)d_in[1];
    const float* W_ih1     = (const float*)d_in[2];
    const float* W_hh1     = (const float*)d_in[3];
    const float* b_ih1     = (const float*)d_in[4];
    const float* b_hh1     = (const float*)d_in[5];
    const float* W_ih2     = (const float*)d_in[6];
    const float* W_hh2     = (const float*)d_in[7];
    const float* b_ih2     = (const float*)d_in[8];
    const float* b_hh2     = (const float*)d_in[9];
    const float* dz_W1     = (const float*)d_in[10];
    const float* dz_b1     = (const float*)d_in[11];
    const float* dz_Wloc   = (const float*)d_in[12];
    const float* dz_bloc   = (const float*)d_in[13];
    const float* dz_Wscale = (const float*)d_in[14];
    const float* dz_bscale = (const float*)d_in[15];
    const float* dx_W1     = (const float*)d_in[16];
    const float* dx_b1     = (const float*)d_in[17];
    const float* dx_Wloc   = (const float*)d_in[18];
    const float* dx_bloc   = (const float*)d_in[19];
    const float* dx_Wscale = (const float*)d_in[20];
    const float* dx_bscale = (const float*)d_in[21];
    const float* h1_0      = (const float*)d_in[22];
    const float* h2_0      = (const float*)d_in[23];

    float* gi2 = (float*)d_ws;   // NB*NT*G2S*4 = 16.8 MB

    gi2_pre<<<2048, 256, 0, stream>>>(x, W_ih2, b_ih2, gi2);
    arfssm<<<NB, 128, 0, stream>>>(gi2, eps, W_ih1, W_hh1, b_ih1, b_hh1,
                                   W_hh2, b_hh2,
                                   dz_W1, dz_b1, dz_Wloc, dz_bloc, dz_Wscale, dz_bscale,
                                   dx_W1, dx_b1, dx_Wloc, dx_bloc, dx_Wscale, dx_bscale,
                                   h1_0, h2_0, (float*)d_out);
}